// Round 3
// baseline (189.488 us; speedup 1.0000x reference)
//
#include <hip/hip_runtime.h>

#define NIMG 64
#define H 512
#define W 512

constexpr float THR_64  = 50.0f / 255.0f;          // level_idx=1: 64x64 details
constexpr float THR_128 = 50.0f / 2.0f / 255.0f;   // level_idx=2: 128x128
constexpr float THR_256 = 50.0f / 4.0f / 255.0f;   // level_idx=3: 256x256

// Weights folded into a single per-thread "comb" accumulator:
//   wav = a3/37748736 + a4/6291456 + a5/786432   (level means + 1/level_idx)
//   tv  = a2/16744448                            (64*511*512, both terms)
//   loss = 1.0*n2v + 0.2*wav + 0.01*tv
constexpr float SC_W1 = 0.2f  / 37748736.0f;
constexpr float SC_W2 = 0.2f  / 6291456.0f;
constexpr float SC_W3 = 0.2f  / 786432.0f;
constexpr float SC_TV = 0.01f / 16744448.0f;

__device__ __forceinline__ float wave_sum(float v) {
#pragma unroll
    for (int o = 32; o > 0; o >>= 1) v += __shfl_down(v, o, 64);
    return v;
}

__device__ __forceinline__ float clip01(float x) {
    return fminf(fmaxf(x, 0.0f), 1.0f);
}

__device__ __forceinline__ float4 clip4(float4 p) {
    p.x = clip01(p.x); p.y = clip01(p.y); p.z = clip01(p.z); p.w = clip01(p.w);
    return p;
}

// Kernel A (wave-local): each wave owns an 8-row x 256-col half-slab; each
// lane owns an 8x4 tile. No __syncthreads in the hot path, no LDS staging.
// All three Haar levels are lane-local (L3 via one shfl_xor across lane
// pairs). TV horizontal uses one shfl_down per row + an 8-lane seam load for
// the col 255|256 boundary; TV vertical is lane-local + 1 halo-row load.
// Per wave: ~17 independent 16B loads issued up front (masks first so the
// sparse noisy loads can issue early), then pure register compute.
__global__ __launch_bounds__(256) void kA(const float* __restrict__ pred,
                                          const float* __restrict__ noisy,
                                          const int* __restrict__ mask,
                                          float4* __restrict__ pA) {
    __shared__ float red[4][3];

    const int tid = threadIdx.x;
    const int lane = tid & 63;
    const int wv = tid >> 6;
    const int gw = (blockIdx.x << 2) + wv;   // global wave id, 0..8191
    const int n = gw >> 7;                   // image (128 waves per image)
    const int u = gw & 127;
    const int s = u >> 1;                    // slab (8 rows)
    const int h = u & 1;                     // column half
    const int r0 = s << 3;                   // first global row
    const int col0 = (h << 8) + (lane << 2); // this lane's first column
    const size_t img = (size_t)n * (H * W);
    const size_t base = img + (size_t)r0 * W + col0;

    // ---------- issue all loads up front (masks first) ----------
    int4 m[8];
#pragma unroll
    for (int r = 0; r < 8; ++r)
        m[r] = *reinterpret_cast<const int4*>(mask + base + (size_t)r * W);

    float4 p[8];
#pragma unroll
    for (int r = 0; r < 8; ++r)
        p[r] = *reinterpret_cast<const float4*>(pred + base + (size_t)r * W);

    // vertical halo row (r0-1)
    float4 hl = make_float4(0.f, 0.f, 0.f, 0.f);
    if (r0 > 0)
        hl = *reinterpret_cast<const float4*>(pred + base - W);

    // seam column 256 (needed by lane 63 of h==0 waves): lanes 0..7 each load
    // one row's value, broadcast later via shfl.
    float smv = 0.f;
    if (h == 0 && lane < 8)
        smv = pred[img + (size_t)(r0 + lane) * W + 256];

    // sparse noisy loads, predicated on mask (~8% of lane-rows active)
    float4 nz[8];
#pragma unroll
    for (int r = 0; r < 8; ++r) {
        nz[r] = make_float4(0.f, 0.f, 0.f, 0.f);
        if ((m[r].x | m[r].y | m[r].z | m[r].w) != 0)
            nz[r] = *reinterpret_cast<const float4*>(noisy + base + (size_t)r * W);
    }

    // ---------- clip ----------
#pragma unroll
    for (int r = 0; r < 8; ++r) p[r] = clip4(p[r]);
    hl = clip4(hl);
    smv = clip01(smv);

    // ---------- TV ----------
    float tv = 0.0f;
#pragma unroll
    for (int r = 0; r < 8; ++r) {
        const float4 q = p[r];
        // horizontal interior
        tv += fabsf(q.y - q.x) + fabsf(q.z - q.y) + fabsf(q.w - q.z);
        // horizontal boundary to next lane; lane 63 h==0 uses seam col 256
        float nb = __shfl_down(q.x, 1, 64);
        float seam_r = __shfl(smv, r, 64);
        if (lane == 63) nb = seam_r;
        if (lane < 63 || h == 0) tv += fabsf(nb - q.w);
    }
    // vertical interior
#pragma unroll
    for (int r = 0; r < 7; ++r) {
        tv += fabsf(p[r + 1].x - p[r].x) + fabsf(p[r + 1].y - p[r].y)
            + fabsf(p[r + 1].z - p[r].z) + fabsf(p[r + 1].w - p[r].w);
    }
    if (r0 > 0) {
        tv += fabsf(p[0].x - hl.x) + fabsf(p[0].y - hl.y)
            + fabsf(p[0].z - hl.z) + fabsf(p[0].w - hl.w);
    }

    // ---------- Haar level 1 (lane-local: 4 row-pairs x 2 col-pairs) ----------
    float ll1[4][2];
    float wav1 = 0.0f;
#pragma unroll
    for (int rp = 0; rp < 4; ++rp) {
        const float4 t = p[2 * rp];
        const float4 bo = p[2 * rp + 1];
        float a, b, c, d, ch, cv, cd;
        a = t.x; b = t.y; c = bo.x; d = bo.y;
        ll1[rp][0] = (a + b + c + d) * 0.5f;
        ch = (a + b - c - d) * 0.5f; cv = (a - b + c - d) * 0.5f; cd = (a - b - c + d) * 0.5f;
        wav1 += fminf(fabsf(ch), THR_256) + fminf(fabsf(cv), THR_256) + fminf(fabsf(cd), THR_256);
        a = t.z; b = t.w; c = bo.z; d = bo.w;
        ll1[rp][1] = (a + b + c + d) * 0.5f;
        ch = (a + b - c - d) * 0.5f; cv = (a - b + c - d) * 0.5f; cd = (a - b - c + d) * 0.5f;
        wav1 += fminf(fabsf(ch), THR_256) + fminf(fabsf(cv), THR_256) + fminf(fabsf(cd), THR_256);
    }

    // ---------- Haar level 2 (lane-local: 2 row-pairs x 1 col-pair) ----------
    float ll2[2];
    float wav2 = 0.0f;
#pragma unroll
    for (int lp = 0; lp < 2; ++lp) {
        const float a = ll1[2 * lp][0], b = ll1[2 * lp][1];
        const float c = ll1[2 * lp + 1][0], d = ll1[2 * lp + 1][1];
        ll2[lp] = (a + b + c + d) * 0.5f;
        const float ch = (a + b - c - d) * 0.5f;
        const float cv = (a - b + c - d) * 0.5f;
        const float cd = (a - b - c + d) * 0.5f;
        wav2 += fminf(fabsf(ch), THR_128) + fminf(fabsf(cv), THR_128) + fminf(fabsf(cd), THR_128);
    }

    // ---------- Haar level 3 (lane-pair via shfl_xor; even lanes own quad) ----------
    float w3 = 0.0f;
    {
        const float b3 = __shfl_xor(ll2[0], 1, 64);
        const float d3 = __shfl_xor(ll2[1], 1, 64);
        if ((lane & 1) == 0) {
            const float a = ll2[0], b = b3, c = ll2[1], d = d3;
            const float ch = (a + b - c - d) * 0.5f;
            const float cv = (a - b + c - d) * 0.5f;
            const float cd = (a - b - c + d) * 0.5f;
            w3 = fminf(fabsf(ch), THR_64) + fminf(fabsf(cv), THR_64)
               + fminf(fabsf(cd), THR_64);
        }
    }

    // ---------- n2v (after Haar so noisy loads have maximal cover) ----------
    float n2v = 0.0f, msum = 0.0f;
#pragma unroll
    for (int r = 0; r < 8; ++r) {
        float mm;
        mm = m[r].x ? 1.f : 0.f; n2v += fabsf(p[r].x - nz[r].x) * mm; msum += mm;
        mm = m[r].y ? 1.f : 0.f; n2v += fabsf(p[r].y - nz[r].y) * mm; msum += mm;
        mm = m[r].z ? 1.f : 0.f; n2v += fabsf(p[r].z - nz[r].z) * mm; msum += mm;
        mm = m[r].w ? 1.f : 0.f; n2v += fabsf(p[r].w - nz[r].w) * mm; msum += mm;
    }

    const float comb = wav1 * SC_W1 + wav2 * SC_W2 + w3 * SC_W3 + tv * SC_TV;

    // ---------- block reduction -> plain stores ----------
    float v0 = wave_sum(n2v);
    float v1 = wave_sum(msum);
    float v2 = wave_sum(comb);
    if (lane == 0) {
        red[wv][0] = v0; red[wv][1] = v1; red[wv][2] = v2;
    }
    __syncthreads();
    if (tid == 0) {
        pA[blockIdx.x] = make_float4(red[0][0] + red[1][0] + red[2][0] + red[3][0],
                                     red[0][1] + red[1][1] + red[2][1] + red[3][1],
                                     red[0][2] + red[1][2] + red[2][2] + red[3][2],
                                     0.0f);
    }
}

// Kernel D: reduce 2048 float4 partials, compose final loss.
__global__ __launch_bounds__(256) void kD(const float4* __restrict__ pA,
                                          float* __restrict__ out) {
    __shared__ float red[4][3];
    const int tid = threadIdx.x;
    const int lane = tid & 63, wv = tid >> 6;

    float s0 = 0, s1 = 0, s2 = 0;
#pragma unroll
    for (int j = 0; j < 8; ++j) {
        float4 v = pA[tid + (j << 8)];
        s0 += v.x; s1 += v.y; s2 += v.z;
    }
    s0 = wave_sum(s0); s1 = wave_sum(s1); s2 = wave_sum(s2);
    if (lane == 0) {
        red[wv][0] = s0; red[wv][1] = s1; red[wv][2] = s2;
    }
    __syncthreads();
    if (tid == 0) {
        float a0 = red[0][0] + red[1][0] + red[2][0] + red[3][0];
        float a1 = red[0][1] + red[1][1] + red[2][1] + red[3][1];
        float a2 = red[0][2] + red[1][2] + red[2][2] + red[3][2];
        out[0] = a0 / fmaxf(a1, 1.0f) + a2;   // n2v + (0.2*wav + 0.01*tv)
    }
}

extern "C" void kernel_launch(void* const* d_in, const int* in_sizes, int n_in,
                              void* d_out, int out_size, void* d_ws, size_t ws_size,
                              hipStream_t stream) {
    (void)in_sizes; (void)n_in; (void)out_size; (void)ws_size;
    const float* pred  = (const float*)d_in[0];
    const float* noisy = (const float*)d_in[1];
    const int*   mask  = (const int*)d_in[2];

    float4* pA = (float4*)d_ws;                           // 2048 * 16 B = 32 KB

    kA<<<2048, 256, 0, stream>>>(pred, noisy, mask, pA);
    kD<<<1, 256, 0, stream>>>(pA, (float*)d_out);
}